// Round 4
// baseline (159.682 us; speedup 1.0000x reference)
//
#include <hip/hip_runtime.h>
#include <math.h>

#define B_SZ 1024
#define E_SZ 512
#define C_SZ 16384
#define MRG 0.1f
#define ALPHA 32.0f
#define K_HY 1.0f
#define LAM 0.1f

typedef __bf16 bf16;
typedef bf16 bf16x8 __attribute__((ext_vector_type(8)));
typedef float f32x4 __attribute__((ext_vector_type(4)));

// ---------------- prologue: proxy-norm + class scalars + zero + convert ----
// blocks [0,4096): proxy row-l2norm -> bf16 (4 rows per block, wave per row)
// blocks [4096,4160): class scalars, zero accumulators, inputs->bf16 (coalesced)
__global__ __launch_bounds__(256) void prologue(
    const float* __restrict__ proxies, bf16* __restrict__ Pbf,
    const float* __restrict__ effNum, const float* __restrict__ lSim,
    const float* __restrict__ x, bf16* __restrict__ Abf,
    float* __restrict__ oSim, float* __restrict__ iEff,
    float* __restrict__ posExp, float* __restrict__ negExp,
    float* __restrict__ negVals, int* __restrict__ cCnt,
    float* __restrict__ acc4) {
    if (blockIdx.x < 4096) {
        int row = (blockIdx.x * 256 + threadIdx.x) >> 6;
        int lane = threadIdx.x & 63;
        const float* pr = proxies + (size_t)row * E_SZ + lane * 8;
        float4 v0 = *(const float4*)pr;
        float4 v1 = *(const float4*)(pr + 4);
        float ss = v0.x * v0.x + v0.y * v0.y + v0.z * v0.z + v0.w * v0.w +
                   v1.x * v1.x + v1.y * v1.y + v1.z * v1.z + v1.w * v1.w;
#pragma unroll
        for (int m = 1; m < 64; m <<= 1) ss += __shfl_xor(ss, m);
        float inv = 1.0f / sqrtf(ss + 1e-12f);
        bf16x8 o;
        o[0] = (bf16)(v0.x * inv); o[1] = (bf16)(v0.y * inv);
        o[2] = (bf16)(v0.z * inv); o[3] = (bf16)(v0.w * inv);
        o[4] = (bf16)(v1.x * inv); o[5] = (bf16)(v1.y * inv);
        o[6] = (bf16)(v1.z * inv); o[7] = (bf16)(v1.w * inv);
        *(bf16x8*)(Pbf + (size_t)row * E_SZ + lane * 8) = o;
    } else {
        int t = (blockIdx.x - 4096) * 256 + threadIdx.x;  // 0..16383
        float en = effNum[t], ls = lSim[t];
        float wb = 1.0f / (1.0f + log1pf(en));
        float eta = (1.0f + K_HY * (1.0f - ls)) * wb + LAM;
        oSim[t] = ls - eta;
        iEff[t] = 1.0f / fmaxf(1.0f, en);
        posExp[t] = 0.f; negExp[t] = 0.f; negVals[t] = 0.f; cCnt[t] = 0;
        if (t < 8) acc4[t] = 0.f;
        // coalesced input conversion: 4 passes x 8 floats (32 B/lane)
#pragma unroll
        for (int p = 0; p < 4; ++p) {
            size_t f0 = ((size_t)p * 16384 + t) * 8;
            float4 v0 = *(const float4*)(x + f0);
            float4 v1 = *(const float4*)(x + f0 + 4);
            bf16x8 o;
            o[0] = (bf16)v0.x; o[1] = (bf16)v0.y; o[2] = (bf16)v0.z; o[3] = (bf16)v0.w;
            o[4] = (bf16)v1.x; o[5] = (bf16)v1.y; o[6] = (bf16)v1.z; o[7] = (bf16)v1.w;
            *(bf16x8*)(Abf + f0) = o;
        }
    }
}

// ---------------- barrier-free register-direct GEMM + epilogue -------------
// Grid (128,8), 256 threads = 4 waves, each wave an independent 64x64 tile.
// Fragments loaded straight from global (L1/L2-served); no LDS, no barriers.
__global__ __launch_bounds__(256) void gemm_epilogue(
    const bf16* __restrict__ Abf,   // [B][E]
    const bf16* __restrict__ Pbf,   // [C][E] normalized
    const int* __restrict__ targets,
    const float* __restrict__ oSimA,
    const float* __restrict__ iEffA,
    float* __restrict__ posExp,
    float* __restrict__ negExp,
    float* __restrict__ negVals,
    int* __restrict__ cCnt) {
    const int tid = threadIdx.x;
    const int wave = tid >> 6, lane = tid & 63;
    const int quad = lane >> 4, l16 = lane & 15;
    const int wRow = (wave >> 1) * 64, wCol = (wave & 1) * 64;
    const int bn0 = blockIdx.x * 128, bm0 = blockIdx.y * 128;

    // fold target counting into one block (cCnt was zeroed by prologue)
    if (blockIdx.x == 0 && blockIdx.y == 0) {
#pragma unroll
        for (int j = 0; j < 4; ++j) atomicAdd(&cCnt[targets[j * 256 + tid]], 1);
    }

    const int aRow = bm0 + wRow + l16;
    const int bCol = bn0 + wCol + l16;
    const bf16* aP[4];
    const bf16* bP[4];
#pragma unroll
    for (int mi = 0; mi < 4; ++mi)
        aP[mi] = Abf + (size_t)(aRow + mi * 16) * E_SZ + quad * 8;
#pragma unroll
    for (int ni = 0; ni < 4; ++ni)
        bP[ni] = Pbf + (size_t)(bCol + ni * 16) * E_SZ + quad * 8;

    f32x4 zero = {0.f, 0.f, 0.f, 0.f};
    f32x4 acc[4][4];
#pragma unroll
    for (int i = 0; i < 4; ++i)
#pragma unroll
        for (int j = 0; j < 4; ++j) acc[i][j] = zero;

#pragma unroll
    for (int k0 = 0; k0 < E_SZ; k0 += 32) {
        bf16x8 af[4], bff[4];
#pragma unroll
        for (int mi = 0; mi < 4; ++mi) af[mi] = *(const bf16x8*)(aP[mi] + k0);
#pragma unroll
        for (int ni = 0; ni < 4; ++ni) bff[ni] = *(const bf16x8*)(bP[ni] + k0);
#pragma unroll
        for (int mi = 0; mi < 4; ++mi)
#pragma unroll
            for (int ni = 0; ni < 4; ++ni)
                acc[mi][ni] = __builtin_amdgcn_mfma_f32_16x16x32_bf16(
                    af[mi], bff[ni], acc[mi][ni], 0, 0, 0);
    }

    // -------- epilogue: per-class (column) reductions --------
    int colG[4]; float oS[4], iE[4];
#pragma unroll
    for (int ni = 0; ni < 4; ++ni) {
        colG[ni] = bn0 + wCol + ni * 16 + l16;
        oS[ni] = oSimA[colG[ni]];
        iE[ni] = iEffA[colG[ni]];
    }
    float negE[4] = {0.f, 0.f, 0.f, 0.f};
    float negV[4] = {0.f, 0.f, 0.f, 0.f};
#pragma unroll
    for (int mi = 0; mi < 4; ++mi) {
#pragma unroll
        for (int r = 0; r < 4; ++r) {
            int rowG = bm0 + wRow + mi * 16 + quad * 4 + r;
            int tgt = targets[rowG];   // broadcast load, L1-hot
#pragma unroll
            for (int ni = 0; ni < 4; ++ni) {
                float cosv = acc[mi][ni][r];
                if (tgt == colG[ni]) {
                    atomicAdd(&posExp[colG[ni]], __expf(ALPHA * (MRG - cosv)));
                } else {
                    float nv = (cosv < oS[ni]) ? iE[ni] : 1.0f;
                    negE[ni] += __expf(ALPHA * (cosv + MRG) * nv);
                    negV[ni] += nv;
                }
            }
        }
    }
#pragma unroll
    for (int ni = 0; ni < 4; ++ni) {
        float e = negE[ni], v = negV[ni];
        e += __shfl_xor(e, 16); e += __shfl_xor(e, 32);
        v += __shfl_xor(v, 16); v += __shfl_xor(v, 32);
        if (quad == 0) {
            atomicAdd(&negExp[colG[ni]], e);
            atomicAdd(&negVals[colG[ni]], v);
        }
    }
}

// ---------------- finalize stage 1: parallel partial reduction -------------
__global__ __launch_bounds__(256) void finalize_partial(
    const float* __restrict__ posExp, const float* __restrict__ negExp,
    const float* __restrict__ negVals, const int* __restrict__ cCnt,
    float* __restrict__ acc4) {
    int c = blockIdx.x * 256 + threadIdx.x;
    float pt = log1pf(posExp[c]);
    float nt = log1pf(negExp[c]);
    int cnt = cCnt[c];
    float pws = (cnt > 0) ? 1.0f : 0.0f;
    int Nc = B_SZ - cnt;
    float nws = (Nc > 0) ? negVals[c] / (float)Nc : 0.0f;
#pragma unroll
    for (int m = 1; m < 64; m <<= 1) {
        pt += __shfl_xor(pt, m);
        nt += __shfl_xor(nt, m);
        pws += __shfl_xor(pws, m);
        nws += __shfl_xor(nws, m);
    }
    __shared__ float red[4][4];
    int wv = threadIdx.x >> 6;
    if ((threadIdx.x & 63) == 0) {
        red[wv][0] = pt; red[wv][1] = nt; red[wv][2] = pws; red[wv][3] = nws;
    }
    __syncthreads();
    if (threadIdx.x < 4) {
        float s = red[0][threadIdx.x] + red[1][threadIdx.x] +
                  red[2][threadIdx.x] + red[3][threadIdx.x];
        atomicAdd(&acc4[threadIdx.x], s);
    }
}

// ---------------- finalize stage 2: scalar output ----------------
__global__ void finalize_out(const float* __restrict__ acc4, float* __restrict__ out) {
    out[0] = acc4[0] / acc4[2] + acc4[1] / acc4[3];
}

extern "C" void kernel_launch(void* const* d_in, const int* in_sizes, int n_in,
                              void* d_out, int out_size, void* d_ws, size_t ws_size,
                              hipStream_t stream) {
    const float* inputs = (const float*)d_in[0];
    const int* targets = (const int*)d_in[1];
    const float* proxies = (const float*)d_in[2];
    const float* effNum = (const float*)d_in[3];
    const float* lSim = (const float*)d_in[4];
    float* out = (float*)d_out;

    // workspace layout
    bf16* Pbf = (bf16*)d_ws;                        // C*E bf16  (16 MB)
    bf16* Abf = Pbf + (size_t)C_SZ * E_SZ;          // B*E bf16  (1 MB)
    float* oSim = (float*)(Abf + (size_t)B_SZ * E_SZ);
    float* iEff = oSim + C_SZ;
    float* posExp = iEff + C_SZ;
    float* negExp = posExp + C_SZ;
    float* negVals = negExp + C_SZ;
    int* cCnt = (int*)(negVals + C_SZ);
    float* acc4 = (float*)(cCnt + C_SZ);

    prologue<<<4096 + 64, 256, 0, stream>>>(proxies, Pbf, effNum, lSim, inputs,
                                            Abf, oSim, iEff, posExp, negExp,
                                            negVals, cCnt, acc4);
    gemm_epilogue<<<dim3(C_SZ / 128, B_SZ / 128), 256, 0, stream>>>(
        Abf, Pbf, targets, oSim, iEff, posExp, negExp, negVals, cCnt);
    finalize_partial<<<C_SZ / 256, 256, 0, stream>>>(posExp, negExp, negVals, cCnt, acc4);
    finalize_out<<<1, 1, 0, stream>>>(acc4, out);
}

// Round 6
// 137.854 us; speedup vs baseline: 1.1583x; 1.1583x over previous
//
#include <hip/hip_runtime.h>
#include <math.h>

#define B_SZ 1024
#define E_SZ 512
#define C_SZ 16384
#define MRG 0.1f
#define ALPHA 32.0f
#define K_HY 1.0f
#define LAM 0.1f

typedef __bf16 bf16;
typedef bf16 bf16x8 __attribute__((ext_vector_type(8)));
typedef float f32x4 __attribute__((ext_vector_type(4)));

__device__ __forceinline__ void async16(const void* g, void* l) {
    __builtin_amdgcn_global_load_lds(
        (const __attribute__((address_space(1))) void*)g,
        (__attribute__((address_space(3))) void*)l,
        16, 0, 0);
}

// ---------------- prologue: one dispatch, 4352 blocks ----------------------
// blocks [0,4096):    proxy row-l2norm -> bf16 (4 rows/block, wave per row)
// blocks [4096,4352): coalesced input convert (8 floats/thread);
//                     threads t<16384 also: class scalars + zero accumulators
__global__ __launch_bounds__(256) void prologue(
    const float* __restrict__ proxies, bf16* __restrict__ Pbf,
    const float* __restrict__ effNum, const float* __restrict__ lSim,
    const float* __restrict__ x, bf16* __restrict__ Abf,
    float* __restrict__ oSim, float* __restrict__ iEff,
    float* __restrict__ posExp, float* __restrict__ negExp,
    float* __restrict__ negVals, int* __restrict__ posCnt,
    float* __restrict__ acc4, int* __restrict__ ticket) {
    if (blockIdx.x < 4096) {
        int row = (blockIdx.x * 256 + threadIdx.x) >> 6;
        int lane = threadIdx.x & 63;
        const float* pr = proxies + (size_t)row * E_SZ + lane * 8;
        float4 v0 = *(const float4*)pr;
        float4 v1 = *(const float4*)(pr + 4);
        float ss = v0.x * v0.x + v0.y * v0.y + v0.z * v0.z + v0.w * v0.w +
                   v1.x * v1.x + v1.y * v1.y + v1.z * v1.z + v1.w * v1.w;
#pragma unroll
        for (int m = 1; m < 64; m <<= 1) ss += __shfl_xor(ss, m);
        float inv = 1.0f / sqrtf(ss + 1e-12f);
        bf16x8 o;
        o[0] = (bf16)(v0.x * inv); o[1] = (bf16)(v0.y * inv);
        o[2] = (bf16)(v0.z * inv); o[3] = (bf16)(v0.w * inv);
        o[4] = (bf16)(v1.x * inv); o[5] = (bf16)(v1.y * inv);
        o[6] = (bf16)(v1.z * inv); o[7] = (bf16)(v1.w * inv);
        *(bf16x8*)(Pbf + (size_t)row * E_SZ + lane * 8) = o;
    } else {
        int t = (blockIdx.x - 4096) * 256 + threadIdx.x;   // 0..65535
        // coalesced input conversion, 8 floats per thread
        size_t f0 = (size_t)t * 8;
        float4 v0 = *(const float4*)(x + f0);
        float4 v1 = *(const float4*)(x + f0 + 4);
        bf16x8 o;
        o[0] = (bf16)v0.x; o[1] = (bf16)v0.y; o[2] = (bf16)v0.z; o[3] = (bf16)v0.w;
        o[4] = (bf16)v1.x; o[5] = (bf16)v1.y; o[6] = (bf16)v1.z; o[7] = (bf16)v1.w;
        *(bf16x8*)(Abf + f0) = o;
        if (t < C_SZ) {
            float en = effNum[t], ls = lSim[t];
            float wb = 1.0f / (1.0f + log1pf(en));
            float eta = (1.0f + K_HY * (1.0f - ls)) * wb + LAM;
            oSim[t] = ls - eta;
            iEff[t] = 1.0f / fmaxf(1.0f, en);
            posExp[t] = 0.f; negExp[t] = 0.f; negVals[t] = 0.f; posCnt[t] = 0;
            if (t < 8) acc4[t] = 0.f;
            if (t == 8) ticket[0] = 0;
        }
    }
}

// ---------------- fused GEMM (bf16 MFMA) + epilogue, double-buffered -------
// Tile: BM=128, BN=128, BK=32. 4 waves x (4x4) 16x16x32 MFMA.
// LDS layout per 16-row chunk: [kq][row], 2-way-only bank aliasing (free).
// Positive-cell counting reproduces count_targets (each (row,tgt) hit once).
__global__ __launch_bounds__(256) void gemm_epilogue(
    const bf16* __restrict__ Abf,   // [B][E]
    const bf16* __restrict__ Pbf,   // [C][E] normalized
    const int* __restrict__ targets,
    const float* __restrict__ oSimA,
    const float* __restrict__ iEffA,
    float* __restrict__ posExp,
    float* __restrict__ negExp,
    float* __restrict__ negVals,
    int* __restrict__ posCnt) {
    __shared__ __align__(16) bf16 Alds[2][128 * 32];
    __shared__ __align__(16) bf16 Blds[2][128 * 32];
    __shared__ int tgtLds[128];

    const int tid = threadIdx.x;
    const int wave = tid >> 6, lane = tid & 63;
    const int quad = lane >> 4, l16 = lane & 15;
    const int wRow = (wave >> 1) * 64, wCol = (wave & 1) * 64;
    const int bn0 = blockIdx.x * 128, bm0 = blockIdx.y * 128;

    if (tid < 128) tgtLds[tid] = targets[bm0 + tid];

    const bf16* gA = Abf + (size_t)(bm0 + wave * 32 + l16) * E_SZ + quad * 8;
    const bf16* gB = Pbf + (size_t)(bn0 + wave * 32 + l16) * E_SZ + quad * 8;

    int colG[4]; float oS[4], iE[4];
#pragma unroll
    for (int ni = 0; ni < 4; ++ni) {
        colG[ni] = bn0 + wCol + ni * 16 + l16;
        oS[ni] = oSimA[colG[ni]];
        iE[ni] = iEffA[colG[ni]];
    }

    f32x4 zero = {0.f, 0.f, 0.f, 0.f};
    f32x4 acc[4][4];
#pragma unroll
    for (int i = 0; i < 4; ++i)
#pragma unroll
        for (int j = 0; j < 4; ++j) acc[i][j] = zero;

#define STAGE(K0, BUF)                                                           \
    {                                                                            \
        _Pragma("unroll")                                                        \
        for (int j = 0; j < 2; ++j) {                                            \
            int chunk = wave * 2 + j;                                            \
            async16(gA + (size_t)j * 16 * E_SZ + (K0), &Alds[BUF][chunk * 512]); \
            async16(gB + (size_t)j * 16 * E_SZ + (K0), &Blds[BUF][chunk * 512]); \
        }                                                                        \
    }

    STAGE(0, 0)
#pragma unroll
    for (int kk = 0; kk < 16; ++kk) {
        __syncthreads();
        if (kk < 15) STAGE((kk + 1) * 32, (kk + 1) & 1)
        const int bsel = kk & 1;
        bf16x8 af[4], bff[4];
#pragma unroll
        for (int mi = 0; mi < 4; ++mi)
            af[mi] = *(const bf16x8*)&Alds[bsel][((wRow >> 4) + mi) * 512 + quad * 128 + l16 * 8];
#pragma unroll
        for (int ni = 0; ni < 4; ++ni)
            bff[ni] = *(const bf16x8*)&Blds[bsel][((wCol >> 4) + ni) * 512 + quad * 128 + l16 * 8];
#pragma unroll
        for (int mi = 0; mi < 4; ++mi)
#pragma unroll
            for (int ni = 0; ni < 4; ++ni)
                acc[mi][ni] = __builtin_amdgcn_mfma_f32_16x16x32_bf16(
                    af[mi], bff[ni], acc[mi][ni], 0, 0, 0);
    }
#undef STAGE

    float negE[4] = {0.f, 0.f, 0.f, 0.f};
    float negV[4] = {0.f, 0.f, 0.f, 0.f};
#pragma unroll
    for (int mi = 0; mi < 4; ++mi) {
#pragma unroll
        for (int r = 0; r < 4; ++r) {
            int rowL = wRow + mi * 16 + quad * 4 + r;
            int tgt = tgtLds[rowL];
#pragma unroll
            for (int ni = 0; ni < 4; ++ni) {
                float cosv = acc[mi][ni][r];
                if (tgt == colG[ni]) {
                    atomicAdd(&posExp[colG[ni]], __expf(ALPHA * (MRG - cosv)));
                    atomicAdd(&posCnt[colG[ni]], 1);
                } else {
                    float nv = (cosv < oS[ni]) ? iE[ni] : 1.0f;
                    negE[ni] += __expf(ALPHA * (cosv + MRG) * nv);
                    negV[ni] += nv;
                }
            }
        }
    }
#pragma unroll
    for (int ni = 0; ni < 4; ++ni) {
        float e = negE[ni], v = negV[ni];
        e += __shfl_xor(e, 16); e += __shfl_xor(e, 32);
        v += __shfl_xor(v, 16); v += __shfl_xor(v, 32);
        if (quad == 0) {
            atomicAdd(&negExp[colG[ni]], e);
            atomicAdd(&negVals[colG[ni]], v);
        }
    }
}

// ---------------- finalize: partial reduction + last-block output ----------
__global__ __launch_bounds__(256) void finalize(
    const float* __restrict__ posExp, const float* __restrict__ negExp,
    const float* __restrict__ negVals, const int* __restrict__ posCnt,
    float* __restrict__ acc4, int* __restrict__ ticket,
    float* __restrict__ out) {
    int tid = threadIdx.x;
    int c = blockIdx.x * 256 + tid;
    float pt = log1pf(posExp[c]);
    float nt = log1pf(negExp[c]);
    int cnt = posCnt[c];
    float pws = (cnt > 0) ? 1.0f : 0.0f;
    int Nc = B_SZ - cnt;
    float nws = (Nc > 0) ? negVals[c] / (float)Nc : 0.0f;
#pragma unroll
    for (int m = 1; m < 64; m <<= 1) {
        pt += __shfl_xor(pt, m);
        nt += __shfl_xor(nt, m);
        pws += __shfl_xor(pws, m);
        nws += __shfl_xor(nws, m);
    }
    __shared__ float red[4][4];
    int wv = tid >> 6;
    if ((tid & 63) == 0) {
        red[wv][0] = pt; red[wv][1] = nt; red[wv][2] = pws; red[wv][3] = nws;
    }
    __syncthreads();
    if (tid < 4) {
        float s = red[0][tid] + red[1][tid] + red[2][tid] + red[3][tid];
        atomicAdd(&acc4[tid], s);
    }
    __syncthreads();
    if (tid == 0) {
        __threadfence();
        int old = atomicAdd(ticket, 1);
        if (old == 63) {
            // L2-coherent reads of the fully-accumulated sums
            float a0 = atomicAdd(&acc4[0], 0.f);
            float a1 = atomicAdd(&acc4[1], 0.f);
            float a2 = atomicAdd(&acc4[2], 0.f);
            float a3 = atomicAdd(&acc4[3], 0.f);
            out[0] = a0 / a2 + a1 / a3;
        }
    }
}

extern "C" void kernel_launch(void* const* d_in, const int* in_sizes, int n_in,
                              void* d_out, int out_size, void* d_ws, size_t ws_size,
                              hipStream_t stream) {
    const float* inputs = (const float*)d_in[0];
    const int* targets = (const int*)d_in[1];
    const float* proxies = (const float*)d_in[2];
    const float* effNum = (const float*)d_in[3];
    const float* lSim = (const float*)d_in[4];
    float* out = (float*)d_out;

    // workspace layout
    bf16* Pbf = (bf16*)d_ws;                        // C*E bf16  (16 MB)
    bf16* Abf = Pbf + (size_t)C_SZ * E_SZ;          // B*E bf16  (1 MB)
    float* oSim = (float*)(Abf + (size_t)B_SZ * E_SZ);
    float* iEff = oSim + C_SZ;
    float* posExp = iEff + C_SZ;
    float* negExp = posExp + C_SZ;
    float* negVals = negExp + C_SZ;
    int* posCnt = (int*)(negVals + C_SZ);
    float* acc4 = (float*)(posCnt + C_SZ);
    int* ticket = (int*)(acc4 + 8);

    prologue<<<4096 + 256, 256, 0, stream>>>(proxies, Pbf, effNum, lSim, inputs,
                                             Abf, oSim, iEff, posExp, negExp,
                                             negVals, posCnt, acc4, ticket);
    gemm_epilogue<<<dim3(C_SZ / 128, B_SZ / 128), 256, 0, stream>>>(
        Abf, Pbf, targets, oSim, iEff, posExp, negExp, negVals, posCnt);
    finalize<<<C_SZ / 256, 256, 0, stream>>>(posExp, negExp, negVals, posCnt,
                                             acc4, ticket, out);
}